// Round 1
// baseline (703.412 us; speedup 1.0000x reference)
//
#include <hip/hip_runtime.h>
#include <hip/hip_bf16.h>
#include <math.h>

// ---------------- problem constants ----------------
#define N_FILT   40
#define FILT_DIM 101
#define FS_F     16000.0f
#define IN_T     160000
#define OUT_T    19988           // (160000 - 101)/8 + 1
#define BATCH    128

// conv tiling
#define TT       512             // output positions per block
#define NTHREADS 256             // 2 outputs per thread
#define NU       525             // per-phase staged x: (TT-1) + 13 + pad

// ---------------------------------------------------------------------------
// Kernel 1: build the 40 x 101 sinc filter bank, store phase-major zero-padded
// filt_phase[p][f][j] = filt[f][8j+p]  (16 floats per (p,f), zero padded)
// ---------------------------------------------------------------------------
__global__ __launch_bounds__(128) void build_filters(
    const float* __restrict__ filt_b1,
    const float* __restrict__ filt_band,
    float* __restrict__ filt_phase /* [8][40][16] */) {
  const int f = blockIdx.x;
  const int k = threadIdx.x;

  const float min_f = 50.0f / FS_F;
  const float beg = fabsf(filt_b1[f]) + min_f;
  const float end = beg + fabsf(filt_band[f]) + min_f;

  // zero the padded taps for this filter (128 entries = 8 phases x 16)
  filt_phase[(((k >> 4) * N_FILT) + f) * 16 + (k & 15)] = 0.0f;

  float bpk = 0.0f;
  float v = -1e30f;
  if (k < FILT_DIM) {
    int d = k - 50; if (d < 0) d = -d;          // distance from center
    float lpE, lpB;
    if (d == 0) { lpE = 2.0f * end; lpB = 2.0f * beg; }
    else {
      const float twoPi = 6.2831853071795864769f;
      float aE = twoPi * end * (float)d;
      float aB = twoPi * beg * (float)d;
      lpE = 2.0f * end * __sinf(aE) / aE;
      lpB = 2.0f * beg * __sinf(aB) / aB;
      // use precise sinf to be safe:
      lpE = 2.0f * end * sinf(aE) / aE;
      lpB = 2.0f * beg * sinf(aB) / aB;
    }
    bpk = lpE - lpB;
    v = bpk;
  }

  // block max-reduce (signed max, matches jnp.max)
  __shared__ float red[128];
  red[k] = v;
  __syncthreads();
  #pragma unroll
  for (int s = 64; s >= 1; s >>= 1) {
    if (k < s) red[k] = fmaxf(red[k], red[k + s]);
    __syncthreads();
  }
  const float mx = red[0];

  if (k < FILT_DIM) {
    // window: n = linspace(0,101,101) -> window[k] = 0.54-0.46*cos(2*pi*k/100)
    const float twoPi = 6.2831853071795864769f;
    float window = 0.54f - 0.46f * cosf(twoPi * (float)k * 0.01f);
    float val = (bpk / mx) * window;
    filt_phase[(((k & 7) * N_FILT) + f) * 16 + (k >> 3)] = val;
  }
}

// ---------------------------------------------------------------------------
// Kernel 2: polyphase strided conv.
// out[b,f,t] = sum_k x[b, 8t+k] * filt[f,k],  k = 8j+p
//            = sum_p sum_j x_p[t+j] * filt_p[f,j]
// Block: one batch b, TT=512 outputs, all 40 filters. 256 threads, 2 t each.
// x staged de-interleaved by phase in LDS; 13-wide window held in registers
// and reused across all 40 filters (acc[2][40] register block).
// ---------------------------------------------------------------------------
__global__ __launch_bounds__(NTHREADS) void sinc_conv_kernel(
    const float* __restrict__ x,
    const float* __restrict__ filt_phase,
    float* __restrict__ out) {
  __shared__ float sxp[8][NU];            // 16.8 KB
  __shared__ float sflt[8][N_FILT][16];   // 20.5 KB

  const int tid = threadIdx.x;
  const int bt  = blockIdx.x;             // t-tile index
  const int b   = blockIdx.y;             // batch
  const long t0 = (long)bt * TT;
  const float* __restrict__ xb = x + (size_t)b * IN_T;

  // ---- stage filters (5120 floats = 1280 float4) ----
  {
    const float4* __restrict__ src = (const float4*)filt_phase;
    float4* dst = (float4*)&sflt[0][0][0];
    #pragma unroll
    for (int i = tid; i < 1280; i += NTHREADS) dst[i] = src[i];
  }

  // ---- stage x, de-interleaved into 8 phases ----
  {
    const long base = 8 * t0;
    for (int i4 = tid; i4 < (NU * 8) / 4; i4 += NTHREADS) {
      long g = base + 4 * (long)i4;
      float4 v = make_float4(0.f, 0.f, 0.f, 0.f);
      if (g + 3 < IN_T) v = *(const float4*)(xb + g);
      int i = 4 * i4;
      sxp[(i    ) & 7][(i    ) >> 3] = v.x;
      sxp[(i + 1) & 7][(i + 1) >> 3] = v.y;
      sxp[(i + 2) & 7][(i + 2) >> 3] = v.z;
      sxp[(i + 3) & 7][(i + 3) >> 3] = v.w;
    }
  }
  __syncthreads();

  float acc[2][N_FILT];
  #pragma unroll
  for (int r = 0; r < 2; ++r)
    #pragma unroll
    for (int f = 0; f < N_FILT; ++f) acc[r][f] = 0.0f;

  #pragma unroll 1          // keep p-loop rolled: I-cache
  for (int p = 0; p < 8; ++p) {
    float wa[13], wb[13];
    #pragma unroll
    for (int j = 0; j < 13; ++j) {
      wa[j] = sxp[p][tid + j];
      wb[j] = sxp[p][tid + NTHREADS + j];
    }
    #pragma unroll
    for (int f = 0; f < N_FILT; ++f) {
      const float4* fp = (const float4*)&sflt[p][f][0];
      float4 f0 = fp[0];
      float4 f1 = fp[1];
      float4 f2 = fp[2];
      float t12 = sflt[p][f][12];
      float a0 = acc[0][f], a1 = acc[1][f];
      a0 = fmaf(wa[0],  f0.x, a0);  a1 = fmaf(wb[0],  f0.x, a1);
      a0 = fmaf(wa[1],  f0.y, a0);  a1 = fmaf(wb[1],  f0.y, a1);
      a0 = fmaf(wa[2],  f0.z, a0);  a1 = fmaf(wb[2],  f0.z, a1);
      a0 = fmaf(wa[3],  f0.w, a0);  a1 = fmaf(wb[3],  f0.w, a1);
      a0 = fmaf(wa[4],  f1.x, a0);  a1 = fmaf(wb[4],  f1.x, a1);
      a0 = fmaf(wa[5],  f1.y, a0);  a1 = fmaf(wb[5],  f1.y, a1);
      a0 = fmaf(wa[6],  f1.z, a0);  a1 = fmaf(wb[6],  f1.z, a1);
      a0 = fmaf(wa[7],  f1.w, a0);  a1 = fmaf(wb[7],  f1.w, a1);
      a0 = fmaf(wa[8],  f2.x, a0);  a1 = fmaf(wb[8],  f2.x, a1);
      a0 = fmaf(wa[9],  f2.y, a0);  a1 = fmaf(wb[9],  f2.y, a1);
      a0 = fmaf(wa[10], f2.z, a0);  a1 = fmaf(wb[10], f2.z, a1);
      a0 = fmaf(wa[11], f2.w, a0);  a1 = fmaf(wb[11], f2.w, a1);
      a0 = fmaf(wa[12], t12,  a0);  a1 = fmaf(wb[12], t12,  a1);
      acc[0][f] = a0; acc[1][f] = a1;
    }
  }

  // ---- store ----
  const long ta = t0 + tid;
  const long tb = t0 + tid + NTHREADS;
  float* __restrict__ ob = out + (size_t)b * N_FILT * (size_t)OUT_T;
  #pragma unroll
  for (int f = 0; f < N_FILT; ++f) {
    if (ta < OUT_T) ob[(size_t)f * OUT_T + ta] = acc[0][f];
    if (tb < OUT_T) ob[(size_t)f * OUT_T + tb] = acc[1][f];
  }
}

// ---------------------------------------------------------------------------
extern "C" void kernel_launch(void* const* d_in, const int* in_sizes, int n_in,
                              void* d_out, int out_size, void* d_ws, size_t ws_size,
                              hipStream_t stream) {
  (void)in_sizes; (void)n_in; (void)out_size; (void)ws_size;
  const float* x     = (const float*)d_in[0];
  const float* fb1   = (const float*)d_in[1];
  const float* fband = (const float*)d_in[2];
  float* filt_phase  = (float*)d_ws;        // 8*40*16 floats = 20.5 KB
  float* out         = (float*)d_out;

  build_filters<<<dim3(N_FILT), dim3(128), 0, stream>>>(fb1, fband, filt_phase);

  dim3 grid((OUT_T + TT - 1) / TT, BATCH);  // 40 x 128
  sinc_conv_kernel<<<grid, dim3(NTHREADS), 0, stream>>>(x, filt_phase, out);
}